// Round 10
// baseline (173.492 us; speedup 1.0000x reference)
//
#include <hip/hip_runtime.h>

// ---------------------------------------------------------------------------
// TripletContrastiveLoss on MI355X (gfx950)  — Round 22
// R21 re-verified the champion (tile 84.7us, total 165.8). Refit model:
// time = staged_bytes / (per-CU rate), where rate depends on pipeline
// independence: R17 barrier-free 40 GB/s/CU, champion 4x4-wave drain 25,
// R13/R14 deep-lockstep 8-9. Untested corner: BIGGER tile at UNCHANGED
// per-wave structure and unchanged 16 waves/CU.
// R22: 256x128 tiles, 8 champion-style waves (wm=w>>1 in 0..3, wn=w&1):
//   * per step stage 24KB (A 16 + F 8) for 128 MFMAs -> 85 FLOP/B,
//     total staged bytes 0.75x champion (384 vs 512 MB)
//   * per-wave loop BYTE-IDENTICAL shape: 4 A-frags + 4 F-frags, 16 MFMA,
//     ONE __syncthreads per step. No setprio/counted-vmcnt (both failed).
//   * VGPR ~108 -> 4 waves/SIMD -> 2 blocks x 8 waves = 16 waves/CU (same
//     TLP as champion); LDS 48KB x 2 fits. Grid 512 = 8 XCD x 64.
// All other kernels + launcher byte-identical to R21 champion.
// ---------------------------------------------------------------------------

#define B_ROWS 8192
#define DIM    1024

typedef __bf16 bf16x8 __attribute__((ext_vector_type(8)));
typedef float  f32x4  __attribute__((ext_vector_type(4)));

__device__ __forceinline__ unsigned short f2bf_rne(float x) {
    unsigned u = __float_as_uint(x);
    unsigned r = (u + 0x7FFFu + ((u >> 16) & 1u)) >> 16;
    return (unsigned short)r;
}
__device__ __forceinline__ float bf2f(unsigned short h) {
    return __uint_as_float(((unsigned)h) << 16);
}

// Async global->LDS, 16 B per lane; contiguous 1 KiB per wave-copy.
__device__ __forceinline__ void async_copy16(const void* g, void* l) {
    __builtin_amdgcn_global_load_lds(
        (const __attribute__((address_space(1))) unsigned int*)g,
        (__attribute__((address_space(3))) unsigned int*)l,
        16, 0, 0);
}

// ---------------------------------------------------------------------------
// Kernel 0: slot assignment + accum/ticket init. A slots ascend from 0;
// F slots DESCEND from 8191 (panel alignment for any nA).  (R18/R21)
// ---------------------------------------------------------------------------
__global__ __launch_bounds__(256) void compute_slots(
    const int* __restrict__ dom, int* __restrict__ slotOf,
    unsigned* __restrict__ cnt, float* __restrict__ accum)
{
    __shared__ int cnts[256];
    __shared__ int base[257];
    const int t = threadIdx.x;

    if (t == 0) {
        cnt[1] = 0u;
        accum[0] = 0.0f;
        accum[1] = 0.0f;
    }

    unsigned mask = 0u; int c = 0;
    #pragma unroll
    for (int i = 0; i < 32; ++i) {
        const int isA = (dom[t + 256 * i] == 0) ? 1 : 0;
        mask |= ((unsigned)isA) << i;
        c += isA;
    }
    cnts[t] = c;
    __syncthreads();
    if (t < 64) {
        const int c0 = cnts[4 * t + 0], c1 = cnts[4 * t + 1];
        const int c2 = cnts[4 * t + 2], c3 = cnts[4 * t + 3];
        const int s4 = c0 + c1 + c2 + c3;
        int sc = s4;
        #pragma unroll
        for (int d = 1; d < 64; d <<= 1) {
            const int o = __shfl_up(sc, d);
            if (t >= d) sc += o;
        }
        const int b = sc - s4;
        base[4 * t + 0] = b;
        base[4 * t + 1] = b + c0;
        base[4 * t + 2] = b + c0 + c1;
        base[4 * t + 3] = b + c0 + c1 + c2;
        if (t == 63) { base[256] = sc; cnt[0] = (unsigned)sc; }
    }
    __syncthreads();
    int aB = base[t];                 // A slots before this thread
    int fI = t * 32 - base[t];        // F rows before this thread (enum order)
    #pragma unroll
    for (int i = 0; i < 32; ++i) {
        const int isA = (mask >> i) & 1;
        slotOf[t + 256 * i] = isA ? aB : (8191 - fI);
        aB += isA;
        fI += 1 - isA;
    }
}

// ---------------------------------------------------------------------------
// Kernel 1: L2-normalize -> bf16, scatter into K-chunk-BLOCKED G2:
//   byte addr = (slot>>7)*262144 + kc*8192 + (slot&127)*64 + inner
// posmin/negmin re-init in place (overlay) after consuming slotOf. (R18/R21)
// ---------------------------------------------------------------------------
__global__ __launch_bounds__(256) void normalize_rows(
    const float* __restrict__ feat, const int* __restrict__ labels,
    int* slotOf /* aliases posmin */, unsigned* __restrict__ negmin,
    unsigned short* __restrict__ G, int* __restrict__ labG,
    float* __restrict__ sqG)
{
    const int wv = threadIdx.x >> 6, lane = threadIdx.x & 63;
    const int row = blockIdx.x * 4 + wv;

    const float4* src = (const float4*)(feat + (size_t)row * DIM);
    float4 v[4];
    float ss = 0.0f;
    #pragma unroll
    for (int j = 0; j < 4; ++j) {
        v[j] = src[j * 64 + lane];
        ss += v[j].x * v[j].x + v[j].y * v[j].y + v[j].z * v[j].z + v[j].w * v[j].w;
    }
    #pragma unroll
    for (int s = 32; s > 0; s >>= 1) ss += __shfl_xor(ss, s);
    const float inv = 1.0f / fmaxf(sqrtf(ss), 1e-12f);

    const int slot = slotOf[row];
    if (lane == 0) {
        ((unsigned*)slotOf)[row] = 0xFFFFFFFFu;   // posmin[row] = +inf bits
        negmin[row] = 0xFFFFFFFFu;
    }
    unsigned short ub[16];
    float ss2 = 0.0f;
    #pragma unroll
    for (int j = 0; j < 4; ++j) {
        const float f0 = v[j].x * inv, f1 = v[j].y * inv,
                    f2 = v[j].z * inv, f3 = v[j].w * inv;
        ub[j * 4 + 0] = f2bf_rne(f0); ub[j * 4 + 1] = f2bf_rne(f1);
        ub[j * 4 + 2] = f2bf_rne(f2); ub[j * 4 + 3] = f2bf_rne(f3);
        #pragma unroll
        for (int q = 0; q < 4; ++q) {
            const float fr = bf2f(ub[j * 4 + q]);
            ss2 += fr * fr;
        }
    }
    #pragma unroll
    for (int s = 32; s > 0; s >>= 1) ss2 += __shfl_xor(ss2, s);
    if (lane == 0) {
        sqG[slot]  = ss2;
        labG[slot] = labels[row];
    }
    char* Gb = (char*)G;
    char* rowBase = Gb + (size_t)(slot >> 7) * 262144 + (size_t)(slot & 127) * 64
                       + (lane & 7) * 8;
    const int kc0 = lane >> 3;                 // 0..7
    #pragma unroll
    for (int j = 0; j < 4; ++j) {
        ushort4 pk;
        pk.x = ub[j * 4 + 0]; pk.y = ub[j * 4 + 1];
        pk.z = ub[j * 4 + 2]; pk.w = ub[j * 4 + 3];
        *(ushort4*)(rowBase + (size_t)(j * 8 + kc0) * 8192) = pk;
    }
}

// ---------------------------------------------------------------------------
// Kernel 2: 256x128 tiles, 8 waves (512 thr), wave (wm=w>>1, wn=w&1) owns a
// 64x64 sub-tile; K=1024 in 32 steps of BK=32. Per step per wave: 3 async
// copies (A-chunks 2w,2w+1 of 16; F-chunk w of 8), 4+4 ds_read_b128 frags,
// 16 MFMA, ONE __syncthreads — champion loop shape exactly.
// LDS: S[2][(256+128)*32 shorts] = 48 KiB (A at 0, F at +8192 shorts).
// A tile = global panels 2tx, 2tx+1 (contiguous 512KB); F panel 63-ty with
// descending-slot reversal (R18-validated). Epilogue = champion, wm in 0..3.
// ---------------------------------------------------------------------------
__global__ __launch_bounds__(512) void tile_mindist(
    const unsigned short* __restrict__ G, const int* __restrict__ labG,
    const float* __restrict__ sqG, const unsigned* __restrict__ cnt,
    unsigned* __restrict__ posmin, unsigned* __restrict__ negmin)
{
    const int nA = (int)cnt[0];
    const int nF = B_ROWS - nA;
    const int nTA = (nA + 255) >> 8;            // 256-row A tiles
    const int nTF = (nF + 127) >> 7;            // 128-row F tiles

    // [buf][A 256 rows | F 128 rows][32 shorts/row] = 49,152 B
    __shared__ __align__(16) unsigned short S[2][384 * 32];
    #define SF_OFF 8192                         // F base in shorts (256*32)

    const int t = threadIdx.x;
    const int lane = t & 63, w = t >> 6;        // 8 waves
    const int wm = w >> 1, wn = w & 1;          // 4 x 2 grid of 64x64 tiles
    const int l15 = lane & 15, quad = lane >> 4;

    // Fragment read offsets (shorts), row stride 32 shorts.
    const int rdA  = (wm * 64 + l15) * 32 + quad * 8;
    const int rdF0 = SF_OFF + ((1 - wn) * 64 + 15 - l15) * 32 + quad * 8;

    const char* Gb = (const char*)G;

    // ---- per-XCD rectangle mapping (validated algebra; bands 2 x 4) ----
    const int xcd = blockIdx.x & 7;
    const int bx  = xcd & 1;                    // tx band (2)
    const int by  = xcd >> 1;                   // ty band (4)
    const int qa = nTA >> 1, ra = nTA & 1;
    const int sa = qa + ((bx < ra) ? 1 : 0);
    const int xa = bx * qa + ((bx < ra) ? bx : ra);
    const int qf = nTF >> 2, rf = nTF & 3;
    const int sf = qf + ((by < rf) ? 1 : 0);
    const int ya = by * qf + ((by < rf) ? by : rf);
    const int localN = sa * sf;
    const int j0 = blockIdx.x >> 3;             // 0..63
    const int jstride = (int)(gridDim.x >> 3);  // 64

    for (int j = j0; j < localN; j += jstride) {
        const int tx = xa + j / sf;             // slow: A-panel pair
        const int ty = ya + j % sf;             // fast: sweep F-band
        const int rowA0  = tx * 256;            // A slot base
        const int rowFl0 = ty * 128;            // F LOCAL base
        const int pA0 = 2 * tx;                 // A panels pA0, pA0+1

        // Per-wave staging sources (contiguous 1 KiB each).
        // A-chunks c0=2w, c0+1 (c>>3 selects panel, c&7 the in-panel chunk).
        const int c0 = 2 * w;
        const char* gA0 = Gb + (size_t)(pA0 + (c0 >> 3)) * 262144
                             + (size_t)(c0 & 7) * 1024 + lane * 16;
        const char* gA1 = Gb + (size_t)(pA0 + ((c0 + 1) >> 3)) * 262144
                             + (size_t)((c0 + 1) & 7) * 1024 + lane * 16;
        const char* gF  = Gb + (size_t)(63 - ty) * 262144
                             + (size_t)w * 1024 + lane * 16;

        f32x4 acc[4][4] = {};

        // Prologue: stage K-chunk 0 into buffer 0 (3 copies per wave).
        async_copy16(gA0, &S[0][c0 * 512]);
        async_copy16(gA1, &S[0][(c0 + 1) * 512]);
        async_copy16(gF,  &S[0][SF_OFF + w * 512]);
        __syncthreads();                         // drains vmcnt (buf0 ready)

        #pragma unroll 4
        for (int step = 0; step < 32; ++step) {
            const int cur = step & 1;
            const int nb = cur ^ 1;
            if (step < 31) {                     // async-stage step+1 into nb
                const size_t off = (size_t)(step + 1) * 8192;
                async_copy16(gA0 + off, &S[nb][c0 * 512]);
                async_copy16(gA1 + off, &S[nb][(c0 + 1) * 512]);
                async_copy16(gF + off,  &S[nb][SF_OFF + w * 512]);
            }

            const unsigned short* pa = &S[cur][rdA];
            const unsigned short* pf = &S[cur][rdF0];
            bf16x8 a[4], b[4];
            #pragma unroll
            for (int fm = 0; fm < 4; ++fm) a[fm] = *(const bf16x8*)(pa + fm * 512);
            #pragma unroll
            for (int fn = 0; fn < 4; ++fn) b[fn] = *(const bf16x8*)(pf + (3 - fn) * 512);
            #pragma unroll
            for (int fm = 0; fm < 4; ++fm)
                #pragma unroll
                for (int fn = 0; fn < 4; ++fn)
                    acc[fm][fn] = __builtin_amdgcn_mfma_f32_16x16x32_bf16(
                        a[fm], b[fn], acc[fm][fn], 0, 0, 0);

            __syncthreads();   // one barrier: completes nb loads, frees cur
        }

        // Epilogue. C/D layout: col = lane&15 (F), row = quad*4+reg (A).
        const float INFV = __uint_as_float(0x7f800000u);
        float sqf[4]; int lf_[4]; bool vf[4];
        #pragma unroll
        for (int fn = 0; fn < 4; ++fn) {
            const int rfl = rowFl0 + wn * 64 + fn * 16 + l15;   // F local
            vf[fn] = rfl < nF;
            const int slotF = 8191 - rfl;       // always in [0,8191]
            sqf[fn] = sqG[slotF];
            lf_[fn] = labG[slotF];
        }
        #pragma unroll
        for (int fm = 0; fm < 4; ++fm) {
            #pragma unroll
            for (int r = 0; r < 4; ++r) {
                const int ra2 = rowA0 + wm * 64 + fm * 16 + quad * 4 + r;
                const bool va = ra2 < nA;
                const int rac = va ? ra2 : 0;
                const float sqa = sqG[rac];
                const int la_ = labG[rac];
                float pmin = INFV, nmin = INFV;
                #pragma unroll
                for (int fn = 0; fn < 4; ++fn) {
                    const float dd = fmaxf(sqa + sqf[fn] - 2.0f * acc[fm][fn][r], 0.0f);
                    if (vf[fn]) {
                        if (la_ == lf_[fn]) pmin = fminf(pmin, dd);
                        else                nmin = fminf(nmin, dd);
                    }
                }
                #pragma unroll
                for (int s = 1; s < 16; s <<= 1) {
                    pmin = fminf(pmin, __shfl_xor(pmin, s));
                    nmin = fminf(nmin, __shfl_xor(nmin, s));
                }
                if (l15 == 0 && va) {
                    if (pmin < INFV) atomicMin(&posmin[ra2], __float_as_uint(pmin));
                    if (nmin < INFV) atomicMin(&negmin[ra2], __float_as_uint(nmin));
                }
            }
        }
        __syncthreads();   // protect LDS before next tile's prologue writes
    }
    #undef SF_OFF
}

// ---------------------------------------------------------------------------
// Kernel 3: hinge + sum/count with fused finalize via device-scope ticket.
// (R16/R18/R21-validated)
// ---------------------------------------------------------------------------
__global__ __launch_bounds__(256) void reduce_loss(
    const unsigned* __restrict__ posmin, const unsigned* __restrict__ negmin,
    float* __restrict__ accum, unsigned* __restrict__ cnt,
    float* __restrict__ out)
{
    const int i = blockIdx.x * 256 + threadIdx.x;
    const unsigned up = posmin[i], un = negmin[i];
    float tl = 0.0f, c = 0.0f;
    if (up != 0xFFFFFFFFu && un != 0xFFFFFFFFu) {
        const float pd = sqrtf(__uint_as_float(up));
        const float nd = sqrtf(__uint_as_float(un));
        tl = fmaxf(pd - nd + 0.3f, 0.0f);
        c = 1.0f;
    }
    #pragma unroll
    for (int s = 32; s > 0; s >>= 1) {
        tl += __shfl_down(tl, s);
        c  += __shfl_down(c, s);
    }
    __shared__ float sb[8];
    const int lane = threadIdx.x & 63, w = threadIdx.x >> 6;
    if (lane == 0) { sb[w] = tl; sb[4 + w] = c; }
    __syncthreads();
    if (threadIdx.x == 0) {
        atomicAdd(&accum[0], sb[0] + sb[1] + sb[2] + sb[3]);
        atomicAdd(&accum[1], sb[4] + sb[5] + sb[6] + sb[7]);
        __threadfence();
        const unsigned ticket = atomicAdd(&cnt[1], 1u);
        if (ticket == 31u) {               // last of the 32 blocks
            __threadfence();
            const float s2 = atomicAdd(&accum[0], 0.0f);
            const float c2 = atomicAdd(&accum[1], 0.0f);
            out[0] = (c2 > 0.0f) ? s2 / fmaxf(c2, 1.0f) : 0.0f;
        }
    }
}

// ---------------------------------------------------------------------------
extern "C" void kernel_launch(void* const* d_in, const int* in_sizes, int n_in,
                              void* d_out, int out_size, void* d_ws, size_t ws_size,
                              hipStream_t stream) {
    const float* feat  = (const float*)d_in[0];
    const int* labels  = (const int*)d_in[1];
    const int* dom     = (const int*)d_in[2];
    float* out = (float*)d_out;

    char* ws = (char*)d_ws;
    // Workspace layout (bytes) — identical footprint to validated layout.
    unsigned short* G   = (unsigned short*)(ws);                 // 16,777,216
    int*      labG      = (int*)(ws + 16777216);                 //     32,768
    float*    sqG       = (float*)(ws + 16809984);               //     32,768
    unsigned* posmin    = (unsigned*)(ws + 16842752);            //     32,768
    unsigned* negmin    = (unsigned*)(ws + 16875520);            //     32,768
    unsigned* cnt       = (unsigned*)(ws + 16908288);            //  8 (nA, ticket)
    float*    accum     = (float*)(ws + 16908296);               //  8 (sum, count)
    // slotOf OVERLAYS posmin (same-address ordering in normalize_rows).
    int*      slotOf    = (int*)(ws + 16842752);

    compute_slots<<<1, 256, 0, stream>>>(dom, slotOf, cnt, accum);
    normalize_rows<<<B_ROWS / 4, 256, 0, stream>>>(feat, labels, slotOf,
                                                   negmin, G, labG, sqG);

    // 512 blocks = 8 XCD groups x 64; 2 blocks/CU (VGPR-capped), grid-stride
    // covers the <=544 worst-case tiles.
    tile_mindist<<<512, 512, 0, stream>>>(G, labG, sqG, cnt, posmin, negmin);

    reduce_loss<<<B_ROWS / 256, 256, 0, stream>>>(posmin, negmin, accum, cnt, out);
}

// Round 11
// 164.529 us; speedup vs baseline: 1.0545x; 1.0545x over previous
//
#include <hip/hip_runtime.h>

// ---------------------------------------------------------------------------
// TripletContrastiveLoss on MI355X (gfx950)  — Round 23
// R22 closed the model: time = staged_traffic / rate(barrier-group size);
// champion (128^2, 4-wave groups) is the measured optimum of that surface.
// Last un-attacked term INSIDE the champion: LDS bank conflicts (4.3M ~ 8%
// of tile cycles; quad reads 16 rows at same K-slot = 8-way conflict).
// R23 single variable: R17-validated both-sides involution key=(row>>1)&3:
//   write: per-lane permutation WITHIN each contiguous 1KB staging chunk
//          (srow*64 + ((lane&3)^((srow>>1)&3))*16) — same lines, same txns
//   read:  phys chunk = quad ^ ((l15>>1)&3) (A), quad ^ (((15-l15)>>1)&3) (F)
// Bank algebra: 8-way -> 2-way (free, m136). All else byte-identical to the
// re-verified R21 champion (tile 84.7us, total 165.8us).
// ---------------------------------------------------------------------------

#define B_ROWS 8192
#define DIM    1024

typedef __bf16 bf16x8 __attribute__((ext_vector_type(8)));
typedef float  f32x4  __attribute__((ext_vector_type(4)));

__device__ __forceinline__ unsigned short f2bf_rne(float x) {
    unsigned u = __float_as_uint(x);
    unsigned r = (u + 0x7FFFu + ((u >> 16) & 1u)) >> 16;
    return (unsigned short)r;
}
__device__ __forceinline__ float bf2f(unsigned short h) {
    return __uint_as_float(((unsigned)h) << 16);
}

// Async global->LDS, 16 B per lane; contiguous 1 KiB per wave-copy (source
// may be lane-permuted within the chunk; dest is always base + lane*16).
__device__ __forceinline__ void async_copy16(const void* g, void* l) {
    __builtin_amdgcn_global_load_lds(
        (const __attribute__((address_space(1))) unsigned int*)g,
        (__attribute__((address_space(3))) unsigned int*)l,
        16, 0, 0);
}

// ---------------------------------------------------------------------------
// Kernel 0: slot assignment + accum/ticket init. A slots ascend from 0;
// F slots DESCEND from 8191 (panel alignment for any nA).  (R18/R21)
// ---------------------------------------------------------------------------
__global__ __launch_bounds__(256) void compute_slots(
    const int* __restrict__ dom, int* __restrict__ slotOf,
    unsigned* __restrict__ cnt, float* __restrict__ accum)
{
    __shared__ int cnts[256];
    __shared__ int base[257];
    const int t = threadIdx.x;

    if (t == 0) {
        cnt[1] = 0u;
        accum[0] = 0.0f;
        accum[1] = 0.0f;
    }

    unsigned mask = 0u; int c = 0;
    #pragma unroll
    for (int i = 0; i < 32; ++i) {
        const int isA = (dom[t + 256 * i] == 0) ? 1 : 0;
        mask |= ((unsigned)isA) << i;
        c += isA;
    }
    cnts[t] = c;
    __syncthreads();
    if (t < 64) {
        const int c0 = cnts[4 * t + 0], c1 = cnts[4 * t + 1];
        const int c2 = cnts[4 * t + 2], c3 = cnts[4 * t + 3];
        const int s4 = c0 + c1 + c2 + c3;
        int sc = s4;
        #pragma unroll
        for (int d = 1; d < 64; d <<= 1) {
            const int o = __shfl_up(sc, d);
            if (t >= d) sc += o;
        }
        const int b = sc - s4;
        base[4 * t + 0] = b;
        base[4 * t + 1] = b + c0;
        base[4 * t + 2] = b + c0 + c1;
        base[4 * t + 3] = b + c0 + c1 + c2;
        if (t == 63) { base[256] = sc; cnt[0] = (unsigned)sc; }
    }
    __syncthreads();
    int aB = base[t];                 // A slots before this thread
    int fI = t * 32 - base[t];        // F rows before this thread (enum order)
    #pragma unroll
    for (int i = 0; i < 32; ++i) {
        const int isA = (mask >> i) & 1;
        slotOf[t + 256 * i] = isA ? aB : (8191 - fI);
        aB += isA;
        fI += 1 - isA;
    }
}

// ---------------------------------------------------------------------------
// Kernel 1: L2-normalize -> bf16, scatter into K-chunk-BLOCKED G2:
//   byte addr = (slot>>7)*262144 + kc*8192 + (slot&127)*64 + inner
// posmin/negmin re-init in place (overlay) after consuming slotOf. (R18/R21)
// ---------------------------------------------------------------------------
__global__ __launch_bounds__(256) void normalize_rows(
    const float* __restrict__ feat, const int* __restrict__ labels,
    int* slotOf /* aliases posmin */, unsigned* __restrict__ negmin,
    unsigned short* __restrict__ G, int* __restrict__ labG,
    float* __restrict__ sqG)
{
    const int wv = threadIdx.x >> 6, lane = threadIdx.x & 63;
    const int row = blockIdx.x * 4 + wv;

    const float4* src = (const float4*)(feat + (size_t)row * DIM);
    float4 v[4];
    float ss = 0.0f;
    #pragma unroll
    for (int j = 0; j < 4; ++j) {
        v[j] = src[j * 64 + lane];
        ss += v[j].x * v[j].x + v[j].y * v[j].y + v[j].z * v[j].z + v[j].w * v[j].w;
    }
    #pragma unroll
    for (int s = 32; s > 0; s >>= 1) ss += __shfl_xor(ss, s);
    const float inv = 1.0f / fmaxf(sqrtf(ss), 1e-12f);

    const int slot = slotOf[row];
    if (lane == 0) {
        ((unsigned*)slotOf)[row] = 0xFFFFFFFFu;   // posmin[row] = +inf bits
        negmin[row] = 0xFFFFFFFFu;
    }
    unsigned short ub[16];
    float ss2 = 0.0f;
    #pragma unroll
    for (int j = 0; j < 4; ++j) {
        const float f0 = v[j].x * inv, f1 = v[j].y * inv,
                    f2 = v[j].z * inv, f3 = v[j].w * inv;
        ub[j * 4 + 0] = f2bf_rne(f0); ub[j * 4 + 1] = f2bf_rne(f1);
        ub[j * 4 + 2] = f2bf_rne(f2); ub[j * 4 + 3] = f2bf_rne(f3);
        #pragma unroll
        for (int q = 0; q < 4; ++q) {
            const float fr = bf2f(ub[j * 4 + q]);
            ss2 += fr * fr;
        }
    }
    #pragma unroll
    for (int s = 32; s > 0; s >>= 1) ss2 += __shfl_xor(ss2, s);
    if (lane == 0) {
        sqG[slot]  = ss2;
        labG[slot] = labels[row];
    }
    char* Gb = (char*)G;
    char* rowBase = Gb + (size_t)(slot >> 7) * 262144 + (size_t)(slot & 127) * 64
                       + (lane & 7) * 8;
    const int kc0 = lane >> 3;                 // 0..7
    #pragma unroll
    for (int j = 0; j < 4; ++j) {
        ushort4 pk;
        pk.x = ub[j * 4 + 0]; pk.y = ub[j * 4 + 1];
        pk.z = ub[j * 4 + 2]; pk.w = ub[j * 4 + 3];
        *(ushort4*)(rowBase + (size_t)(j * 8 + kc0) * 8192) = pk;
    }
}

// ---------------------------------------------------------------------------
// Kernel 2: persistent 128x128 tiles, 4 waves (each 64x64 via 4x4 of
// 16x16x32 bf16 MFMA), K=1024 in 32 steps of BK=32. (champion structure)
// NEW vs R21: both-sides bank swizzle, key(row) = (row>>1)&3.
//   LDS phys slot p of row u holds global K-slice p ^ key(u):
//   write: lane reads source byte srow*64 + ((lane&3)^((srow>>1)&3))*16
//          (permutation within the contiguous 1KB chunk; dest unchanged)
//   read:  A: chunk = quad ^ ((l15>>1)&3); F: chunk = quad ^ (((15-l15)>>1)&3)
// Bank pattern per quad-read: 8-way -> 2-way (free).
// ---------------------------------------------------------------------------
__global__ __launch_bounds__(256) void tile_mindist(
    const unsigned short* __restrict__ G, const int* __restrict__ labG,
    const float* __restrict__ sqG, const unsigned* __restrict__ cnt,
    unsigned* __restrict__ posmin, unsigned* __restrict__ negmin)
{
    const int nA = (int)cnt[0];
    const int nF = B_ROWS - nA;
    const int nTA = (nA + 127) >> 7;
    const int nTF = (nF + 127) >> 7;

    // [buf][A=0/F=1][128 rows x 32 shorts (64 B, unpadded)] = 32,768 B
    __shared__ __align__(16) unsigned short S[2][2][128 * 32];

    const int t = threadIdx.x;
    const int lane = t & 63, w = t >> 6;
    const int wm = w >> 1, wn = w & 1;          // wave sub-tile coords (x64)
    const int l15 = lane & 15, quad = lane >> 4;

    // Staging: wave w owns chunks 2w, 2w+1 (16 rows x 64 B each, contiguous).
    const int ch0 = 2 * w;
    // Swizzled source offset within a 1KB chunk (key = (srow>>1)&3):
    const int srow = lane >> 2;
    const int scs  = srow * 64 + ((((lane & 3) ^ ((srow >> 1) & 3))) << 4);

    // Fragment read offsets (shorts), row stride 32 shorts; swizzled chunk.
    const int kA   = (l15 >> 1) & 3;
    const int rdA  = (wm * 64 + l15) * 32 + ((quad ^ kA) << 3);
    const int kF   = ((15 - l15) >> 1) & 3;
    const int rdF0 = ((1 - wn) * 64 + 15 - l15) * 32 + ((quad ^ kF) << 3);

    const char* Gb = (const char*)G;

    // ---- per-XCD rectangle mapping (R16-validated algebra) ----
    const int xcd = blockIdx.x & 7;
    const int bx  = xcd & 1;                    // tx band (2)
    const int by  = xcd >> 1;                   // ty band (4)
    const int qa = nTA >> 1, ra = nTA & 1;
    const int sa = qa + ((bx < ra) ? 1 : 0);
    const int xa = bx * qa + ((bx < ra) ? bx : ra);
    const int qf = nTF >> 2, rf = nTF & 3;
    const int sf = qf + ((by < rf) ? 1 : 0);
    const int ya = by * qf + ((by < rf) ? by : rf);
    const int localN = sa * sf;
    const int j0 = blockIdx.x >> 3;             // 0..131
    const int jstride = (int)(gridDim.x >> 3);  // 132

    for (int j = j0; j < localN; j += jstride) {
        const int tx = xa + j / sf;             // slow: A-panel
        const int ty = ya + j % sf;             // fast: sweep F-band
        const int rowA0  = tx * 128;            // A slot base
        const int rowFl0 = ty * 128;            // F LOCAL base

        // Contiguous panel bases (blocked layout), swizzled source offset.
        const char* baseA = Gb + (size_t)tx * 262144 + (size_t)(ch0 * 1024) + scs;
        const char* baseF = Gb + (size_t)(63 - ty) * 262144 + (size_t)(ch0 * 1024) + scs;

        f32x4 acc[4][4] = {};

        // Prologue: stage K-chunk 0 into buffer 0.
        #pragma unroll
        for (int h = 0; h < 2; ++h) {
            async_copy16(baseA + h * 1024, &S[0][0][(ch0 + h) * 512]);
            async_copy16(baseF + h * 1024, &S[0][1][(ch0 + h) * 512]);
        }
        __syncthreads();                         // drains vmcnt (buf0 ready)

        #pragma unroll 4
        for (int step = 0; step < 32; ++step) {
            const int cur = step & 1;
            const int nb = cur ^ 1;
            if (step < 31) {                     // async-stage step+1 into nb
                const size_t off = (size_t)(step + 1) * 8192;
                #pragma unroll
                for (int h = 0; h < 2; ++h) {
                    async_copy16(baseA + off + h * 1024, &S[nb][0][(ch0 + h) * 512]);
                    async_copy16(baseF + off + h * 1024, &S[nb][1][(ch0 + h) * 512]);
                }
            }

            const unsigned short* pa = &S[cur][0][rdA];
            const unsigned short* pf = &S[cur][1][rdF0];
            bf16x8 a[4], b[4];
            #pragma unroll
            for (int fm = 0; fm < 4; ++fm) a[fm] = *(const bf16x8*)(pa + fm * 512);
            #pragma unroll
            for (int fn = 0; fn < 4; ++fn) b[fn] = *(const bf16x8*)(pf + (3 - fn) * 512);
            #pragma unroll
            for (int fm = 0; fm < 4; ++fm)
                #pragma unroll
                for (int fn = 0; fn < 4; ++fn)
                    acc[fm][fn] = __builtin_amdgcn_mfma_f32_16x16x32_bf16(
                        a[fm], b[fn], acc[fm][fn], 0, 0, 0);

            __syncthreads();   // one barrier: completes nb loads, frees cur
        }

        // Epilogue. C/D layout: col = lane&15 (F), row = quad*4+reg (A).
        const float INFV = __uint_as_float(0x7f800000u);
        float sqf[4]; int lf_[4]; bool vf[4];
        #pragma unroll
        for (int fn = 0; fn < 4; ++fn) {
            const int rfl = rowFl0 + wn * 64 + fn * 16 + l15;   // F local
            vf[fn] = rfl < nF;
            const int slotF = 8191 - rfl;       // always in [0,8191]
            sqf[fn] = sqG[slotF];
            lf_[fn] = labG[slotF];
        }
        #pragma unroll
        for (int fm = 0; fm < 4; ++fm) {
            #pragma unroll
            for (int r = 0; r < 4; ++r) {
                const int ra2 = rowA0 + wm * 64 + fm * 16 + quad * 4 + r;
                const bool va = ra2 < nA;
                const int rac = va ? ra2 : 0;
                const float sqa = sqG[rac];
                const int la_ = labG[rac];
                float pmin = INFV, nmin = INFV;
                #pragma unroll
                for (int fn = 0; fn < 4; ++fn) {
                    const float dd = fmaxf(sqa + sqf[fn] - 2.0f * acc[fm][fn][r], 0.0f);
                    if (vf[fn]) {
                        if (la_ == lf_[fn]) pmin = fminf(pmin, dd);
                        else                nmin = fminf(nmin, dd);
                    }
                }
                #pragma unroll
                for (int s = 1; s < 16; s <<= 1) {
                    pmin = fminf(pmin, __shfl_xor(pmin, s));
                    nmin = fminf(nmin, __shfl_xor(nmin, s));
                }
                if (l15 == 0 && va) {
                    if (pmin < INFV) atomicMin(&posmin[ra2], __float_as_uint(pmin));
                    if (nmin < INFV) atomicMin(&negmin[ra2], __float_as_uint(nmin));
                }
            }
        }
        __syncthreads();   // protect LDS before next tile's prologue writes
    }
}

// ---------------------------------------------------------------------------
// Kernel 3: hinge + sum/count with fused finalize via device-scope ticket.
// (R16/R18/R21-validated)
// ---------------------------------------------------------------------------
__global__ __launch_bounds__(256) void reduce_loss(
    const unsigned* __restrict__ posmin, const unsigned* __restrict__ negmin,
    float* __restrict__ accum, unsigned* __restrict__ cnt,
    float* __restrict__ out)
{
    const int i = blockIdx.x * 256 + threadIdx.x;
    const unsigned up = posmin[i], un = negmin[i];
    float tl = 0.0f, c = 0.0f;
    if (up != 0xFFFFFFFFu && un != 0xFFFFFFFFu) {
        const float pd = sqrtf(__uint_as_float(up));
        const float nd = sqrtf(__uint_as_float(un));
        tl = fmaxf(pd - nd + 0.3f, 0.0f);
        c = 1.0f;
    }
    #pragma unroll
    for (int s = 32; s > 0; s >>= 1) {
        tl += __shfl_down(tl, s);
        c  += __shfl_down(c, s);
    }
    __shared__ float sb[8];
    const int lane = threadIdx.x & 63, w = threadIdx.x >> 6;
    if (lane == 0) { sb[w] = tl; sb[4 + w] = c; }
    __syncthreads();
    if (threadIdx.x == 0) {
        atomicAdd(&accum[0], sb[0] + sb[1] + sb[2] + sb[3]);
        atomicAdd(&accum[1], sb[4] + sb[5] + sb[6] + sb[7]);
        __threadfence();
        const unsigned ticket = atomicAdd(&cnt[1], 1u);
        if (ticket == 31u) {               // last of the 32 blocks
            __threadfence();
            const float s2 = atomicAdd(&accum[0], 0.0f);
            const float c2 = atomicAdd(&accum[1], 0.0f);
            out[0] = (c2 > 0.0f) ? s2 / fmaxf(c2, 1.0f) : 0.0f;
        }
    }
}

// ---------------------------------------------------------------------------
extern "C" void kernel_launch(void* const* d_in, const int* in_sizes, int n_in,
                              void* d_out, int out_size, void* d_ws, size_t ws_size,
                              hipStream_t stream) {
    const float* feat  = (const float*)d_in[0];
    const int* labels  = (const int*)d_in[1];
    const int* dom     = (const int*)d_in[2];
    float* out = (float*)d_out;

    char* ws = (char*)d_ws;
    // Workspace layout (bytes) — identical footprint to validated layout.
    // G is the K-chunk-BLOCKED G2: 64 panels x 256 KiB = 16,777,216 B.
    unsigned short* G   = (unsigned short*)(ws);                 // 16,777,216
    int*      labG      = (int*)(ws + 16777216);                 //     32,768
    float*    sqG       = (float*)(ws + 16809984);               //     32,768
    unsigned* posmin    = (unsigned*)(ws + 16842752);            //     32,768
    unsigned* negmin    = (unsigned*)(ws + 16875520);            //     32,768
    unsigned* cnt       = (unsigned*)(ws + 16908288);            //  8 (nA, ticket)
    float*    accum     = (float*)(ws + 16908296);               //  8 (sum, count)
    // slotOf OVERLAYS posmin (same-address ordering in normalize_rows).
    int*      slotOf    = (int*)(ws + 16842752);

    compute_slots<<<1, 256, 0, stream>>>(dom, slotOf, cnt, accum);
    normalize_rows<<<B_ROWS / 4, 256, 0, stream>>>(feat, labels, slotOf,
                                                   negmin, G, labG, sqG);

    // Grid 1056 = 8 XCD groups x 132; per-XCD rectangle mapping in-kernel.
    tile_mindist<<<1056, 256, 0, stream>>>(G, labG, sqG, cnt, posmin, negmin);

    reduce_loss<<<B_ROWS / 256, 256, 0, stream>>>(posmin, negmin, accum, cnt, out);
}